// Round 1
// baseline (702.568 us; speedup 1.0000x reference)
//
#include <hip/hip_runtime.h>

// Sizes: N=500000, C=128, H=256, A=10, E=600000, B=50000.
// R4: wide-load readout (16B/lane), xw pre-scaled by dinv[src] in gemm
// epilogue (dinv factors out of aggregation), merged deg+link kernel.
// R5 (this round): identical resubmit — previous bench was an infra failure
// ("MI355X container failed twice"); need baseline counters before editing.

typedef __bf16 bf16x8 __attribute__((ext_vector_type(8)));
typedef float f32x4 __attribute__((ext_vector_type(4)));

// ---- per-edge: degree count + adjacency linked list -------------------------
__global__ __launch_bounds__(256) void k_edges(const int* __restrict__ dst, int E,
                                               int* __restrict__ deg,
                                               int* __restrict__ head,
                                               int* __restrict__ nxt) {
    int e = blockIdx.x * 256 + threadIdx.x;
    if (e < E) {
        int d = dst[e];
        atomicAdd(&deg[d], 1);
        nxt[e] = atomicExch(&head[d], e);
    }
}

// ---- dinv = rsqrt(deg + 1)  (+1 = self loop) --------------------------------
__global__ __launch_bounds__(256) void k_dinv(const int* __restrict__ deg,
                                              float* __restrict__ dinv, int N) {
    int i = blockIdx.x * 256 + threadIdx.x;
    if (i < N) dinv[i] = rsqrtf((float)deg[i] + 1.0f);
}

// ---- transpose-convert weights: Wt[n*K+k] = bf16(W[k*Nc+n]) -----------------
__global__ __launch_bounds__(256) void k_tconv(const float* __restrict__ W,
                                               __bf16* __restrict__ Wt,
                                               int kbits, int total, int Nc) {
    int i = blockIdx.x * 256 + threadIdx.x;
    if (i < total) {
        int n = i >> kbits;
        int k = i & ((1 << kbits) - 1);
        Wt[i] = (__bf16)W[(long)k * Nc + n];
    }
}

// ---- xws = bf16( dinv[row] * (state @ W_gcn) )  via MFMA 16x16x32 bf16 ------
__global__ __launch_bounds__(256) void k_gemm(const float* __restrict__ X,
                                              const __bf16* __restrict__ Wt,
                                              const float* __restrict__ dinv,
                                              __bf16* __restrict__ Y, int N) {
    int wave = threadIdx.x >> 6;
    int lane = threadIdx.x & 63;
    long row0 = (long)blockIdx.x * 64 + wave * 16;
    if (row0 >= N) return;
    int m = lane & 15;
    int quad = lane >> 4;
    f32x4 acc[8] = {};
    #pragma unroll
    for (int kt = 0; kt < 4; kt++) {
        int k0 = kt * 32 + quad * 8;
        const float* ap = X + (row0 + m) * 128 + k0;
        float4 lo = *(const float4*)ap;
        float4 hi = *(const float4*)(ap + 4);
        bf16x8 a = {(__bf16)lo.x, (__bf16)lo.y, (__bf16)lo.z, (__bf16)lo.w,
                    (__bf16)hi.x, (__bf16)hi.y, (__bf16)hi.z, (__bf16)hi.w};
        #pragma unroll
        for (int t = 0; t < 8; t++) {
            bf16x8 b = *(const bf16x8*)(Wt + (t * 16 + m) * 128 + k0);
            acc[t] = __builtin_amdgcn_mfma_f32_16x16x32_bf16(a, b, acc[t], 0, 0, 0);
        }
    }
    float dv[4];
    #pragma unroll
    for (int r = 0; r < 4; r++) dv[r] = dinv[row0 + quad * 4 + r];
    #pragma unroll
    for (int t = 0; t < 8; t++)
        #pragma unroll
        for (int r = 0; r < 4; r++)
            Y[(row0 + quad * 4 + r) * 128 + t * 16 + m] =
                (__bf16)(acc[t][r] * dv[r]);
}

// ---- fused aggregate + relu + residual + action-weighted readout ------------
// One block per b. 128 thr = 8 node slots x 16 lanes; lane owns 8 channels.
__global__ __launch_bounds__(128) void k_readout(const int* __restrict__ head,
                                                 const int* __restrict__ nxt,
                                                 const int* __restrict__ e_src,
                                                 const float* __restrict__ dinv,
                                                 const __bf16* __restrict__ xws,
                                                 const float* __restrict__ state,
                                                 const float* __restrict__ bgcn,
                                                 const float* __restrict__ action,
                                                 __bf16* __restrict__ xB, int B) {
    __shared__ float red[16][8];
    int b = blockIdx.x;
    int tid = threadIdx.x;
    int lane16 = tid & 15;
    int slot = tid >> 4;       // 0..7
    int c0 = lane16 * 8;
    float4 bg0 = *(const float4*)(bgcn + c0);
    float4 bg1 = *(const float4*)(bgcn + c0 + 4);
    float bg[8] = {bg0.x, bg0.y, bg0.z, bg0.w, bg1.x, bg1.y, bg1.z, bg1.w};
    float acc[8] = {};
    for (int a = slot; a < 10; a += 8) {
        int n = b * 10 + a;
        // sum of pre-scaled rows: self + in-edges (dinv[n] factored out)
        float s[8];
        bf16x8 x = *(const bf16x8*)(xws + (size_t)n * 128 + c0);
        #pragma unroll
        for (int k = 0; k < 8; k++) s[k] = (float)x[k];
        for (int j = head[n]; j >= 0; j = nxt[j]) {
            int sr = e_src[j];
            bf16x8 g = *(const bf16x8*)(xws + (size_t)sr * 128 + c0);
            #pragma unroll
            for (int k = 0; k < 8; k++) s[k] += (float)g[k];
        }
        float di = dinv[n];
        float aw = action[n] * 10.f;
        float4 st0 = *(const float4*)(state + (size_t)n * 128 + c0);
        float4 st1 = *(const float4*)(state + (size_t)n * 128 + c0 + 4);
        float st[8] = {st0.x, st0.y, st0.z, st0.w, st1.x, st1.y, st1.z, st1.w};
        #pragma unroll
        for (int k = 0; k < 8; k++)
            acc[k] += aw * (fmaxf(di * s[k] + bg[k], 0.f) + st[k]);
    }
    // reduce 8 slots -> 1: shuffle over slots within wave, LDS across waves
    #pragma unroll
    for (int k = 0; k < 8; k++) {
        acc[k] += __shfl_down(acc[k], 32);
        acc[k] += __shfl_down(acc[k], 16);
    }
    if (tid >= 64 && tid < 80) {
        #pragma unroll
        for (int k = 0; k < 8; k++) red[tid - 64][k] = acc[k];
    }
    __syncthreads();
    if (tid < 16) {
        bf16x8 o;
        #pragma unroll
        for (int k = 0; k < 8; k++) o[k] = (__bf16)(acc[k] + red[tid][k]);
        *(bf16x8*)(xB + (size_t)b * 128 + c0) = o;
    }
}

// ---- MLP head via MFMA: relu(x@W1+b1) -> relu(@W2+b2) -> @W3+b3 -------------
__global__ __launch_bounds__(256) void k_mlp(const __bf16* __restrict__ xB,
                                             const __bf16* __restrict__ W1t,
                                             const float* __restrict__ b1,
                                             const __bf16* __restrict__ W2t,
                                             const float* __restrict__ b2,
                                             const float* __restrict__ W3,
                                             const float* __restrict__ b3,
                                             float* __restrict__ out, int B) {
    __shared__ __bf16 hs[16][264];
    __shared__ float osum[4][16];
    int wave = threadIdx.x >> 6;
    int lane = threadIdx.x & 63;
    int m = lane & 15;
    int quad = lane >> 4;
    long r0 = (long)blockIdx.x * 16;

    f32x4 acc[4] = {};
    #pragma unroll
    for (int kt = 0; kt < 4; kt++) {
        int k0 = kt * 32 + quad * 8;
        bf16x8 a = *(const bf16x8*)(xB + (r0 + m) * 128 + k0);
        #pragma unroll
        for (int t = 0; t < 4; t++) {
            int n = wave * 64 + t * 16 + m;
            bf16x8 b = *(const bf16x8*)(W1t + (long)n * 128 + k0);
            acc[t] = __builtin_amdgcn_mfma_f32_16x16x32_bf16(a, b, acc[t], 0, 0, 0);
        }
    }
    #pragma unroll
    for (int t = 0; t < 4; t++) {
        int n = wave * 64 + t * 16 + m;
        float bb = b1[n];
        #pragma unroll
        for (int r = 0; r < 4; r++)
            hs[quad * 4 + r][n] = (__bf16)fmaxf(acc[t][r] + bb, 0.f);
    }
    __syncthreads();

    f32x4 acc2[4] = {};
    #pragma unroll
    for (int kt = 0; kt < 8; kt++) {
        int k0 = kt * 32 + quad * 8;
        bf16x8 a = *(const bf16x8*)(&hs[m][k0]);
        #pragma unroll
        for (int t = 0; t < 4; t++) {
            int n = wave * 64 + t * 16 + m;
            bf16x8 b = *(const bf16x8*)(W2t + (long)n * 256 + k0);
            acc2[t] = __builtin_amdgcn_mfma_f32_16x16x32_bf16(a, b, acc2[t], 0, 0, 0);
        }
    }

    float part[4] = {0.f, 0.f, 0.f, 0.f};
    #pragma unroll
    for (int t = 0; t < 4; t++) {
        int n = wave * 64 + t * 16 + m;
        float bb = b2[n], w3 = W3[n];
        #pragma unroll
        for (int r = 0; r < 4; r++)
            part[r] += fmaxf(acc2[t][r] + bb, 0.f) * w3;
    }
    #pragma unroll
    for (int off = 8; off; off >>= 1)
        #pragma unroll
        for (int r = 0; r < 4; r++)
            part[r] += __shfl_down(part[r], off, 16);
    if (m == 0) {
        #pragma unroll
        for (int r = 0; r < 4; r++) osum[wave][quad * 4 + r] = part[r];
    }
    __syncthreads();
    if (threadIdx.x < 16)
        out[r0 + threadIdx.x] = osum[0][threadIdx.x] + osum[1][threadIdx.x] +
                                osum[2][threadIdx.x] + osum[3][threadIdx.x] + b3[0];
}

extern "C" void kernel_launch(void* const* d_in, const int* in_sizes, int n_in,
                              void* d_out, int out_size, void* d_ws, size_t ws_size,
                              hipStream_t stream) {
    const float* state  = (const float*)d_in[0];
    const int*   edge   = (const int*)d_in[1];   // [2, E]: src row then dst row
    const float* action = (const float*)d_in[2];
    const float* W_gcn  = (const float*)d_in[3];
    const float* b_gcn  = (const float*)d_in[4];
    const float* W1     = (const float*)d_in[5];
    const float* b1     = (const float*)d_in[6];
    const float* W2     = (const float*)d_in[7];
    const float* b2     = (const float*)d_in[8];
    const float* W3     = (const float*)d_in[9];
    const float* b3     = (const float*)d_in[10];
    float* out = (float*)d_out;

    int N = in_sizes[0] / 128;
    int E = in_sizes[1] / 2;
    int B = out_size;
    const int* e_src = edge;
    const int* e_dst = edge + E;

    // workspace: xws bf16[N*128] | xB bf16[B*128] | Wgt bf16[128*128]
    //          | W1t bf16[256*128] | W2t bf16[256*256]
    //          | dinv f32[N] | deg i32[N] | head i32[N] | nxt i32[E]
    __bf16* xws = (__bf16*)d_ws;
    __bf16* xB  = xws + (size_t)N * 128;
    __bf16* Wgt = xB + (size_t)B * 128;
    __bf16* W1t = Wgt + 128 * 128;
    __bf16* W2t = W1t + 256 * 128;
    float* dinv = (float*)(W2t + 256 * 256);
    int*   deg  = (int*)(dinv + N);
    int*   head = deg + N;
    int*   nxt  = head + N;

    hipMemsetAsync(deg, 0, (size_t)N * sizeof(int), stream);
    hipMemsetAsync(head, 0xFF, (size_t)N * sizeof(int), stream);  // -1

    k_tconv<<<(128 * 128 + 255) / 256, 256, 0, stream>>>(W_gcn, Wgt, 7, 128 * 128, 128);
    k_tconv<<<(256 * 128 + 255) / 256, 256, 0, stream>>>(W1, W1t, 7, 256 * 128, 256);
    k_tconv<<<(256 * 256 + 255) / 256, 256, 0, stream>>>(W2, W2t, 8, 256 * 256, 256);
    k_edges<<<(E + 255) / 256, 256, 0, stream>>>(e_dst, E, deg, head, nxt);
    k_dinv<<<(N + 255) / 256, 256, 0, stream>>>(deg, dinv, N);
    k_gemm<<<(N + 63) / 64, 256, 0, stream>>>(state, Wgt, dinv, xws, N);
    k_readout<<<B, 128, 0, stream>>>(head, nxt, e_src, dinv, xws, state, b_gcn,
                                     action, xB, B);
    k_mlp<<<B / 16, 256, 0, stream>>>(xB, W1t, b1, W2t, b2, W3, b3, out, B);
}

// Round 2
// 648.520 us; speedup vs baseline: 1.0833x; 1.0833x over previous
//
#include <hip/hip_runtime.h>

// Sizes: N=500000, C=128, H=256, A=10, E=600000, B=50000.
// R4: wide-load readout (16B/lane), xw pre-scaled by dinv[src] in gemm.
// R6 (this round): k_gemm rewrite — baseline counters showed it latency-bound
// (177us, 18% HBM, MfmaUtil 3.6%, VALUBusy 6.6%, VGPR=64 capping prefetch ILP).
//   - W^T held entirely in registers (32 frags = 128 VGPRs, loaded once/wave)
//   - grid-stride row-tile loop, double-buffered A loads (named bufs, static idx)
//   - swapped MFMA operands: D[channel][row] layout -> lane owns one row,
//     1 dinv scalar + 8x8B stores instead of 4 dinv + 32x2B stores.

typedef __bf16 bf16x8 __attribute__((ext_vector_type(8)));
typedef __bf16 bf16x4 __attribute__((ext_vector_type(4)));
typedef float f32x4 __attribute__((ext_vector_type(4)));

// ---- per-edge: degree count + adjacency linked list -------------------------
__global__ __launch_bounds__(256) void k_edges(const int* __restrict__ dst, int E,
                                               int* __restrict__ deg,
                                               int* __restrict__ head,
                                               int* __restrict__ nxt) {
    int e = blockIdx.x * 256 + threadIdx.x;
    if (e < E) {
        int d = dst[e];
        atomicAdd(&deg[d], 1);
        nxt[e] = atomicExch(&head[d], e);
    }
}

// ---- dinv = rsqrt(deg + 1)  (+1 = self loop) --------------------------------
__global__ __launch_bounds__(256) void k_dinv(const int* __restrict__ deg,
                                              float* __restrict__ dinv, int N) {
    int i = blockIdx.x * 256 + threadIdx.x;
    if (i < N) dinv[i] = rsqrtf((float)deg[i] + 1.0f);
}

// ---- transpose-convert weights: Wt[n*K+k] = bf16(W[k*Nc+n]) -----------------
__global__ __launch_bounds__(256) void k_tconv(const float* __restrict__ W,
                                               __bf16* __restrict__ Wt,
                                               int kbits, int total, int Nc) {
    int i = blockIdx.x * 256 + threadIdx.x;
    if (i < total) {
        int n = i >> kbits;
        int k = i & ((1 << kbits) - 1);
        Wt[i] = (__bf16)W[(long)k * Nc + n];
    }
}

// ---- xws = bf16( dinv[row] * (state @ W_gcn) )  via MFMA 16x16x32 bf16 ------
// One wave owns 16-row tiles (grid-stride). W^T fragments live in registers for
// the whole kernel; A (state) is double-buffered 8xfloat4 per lane.
__global__ __launch_bounds__(256, 2) void k_gemm(const float* __restrict__ X,
                                                 const __bf16* __restrict__ Wt,
                                                 const float* __restrict__ dinv,
                                                 __bf16* __restrict__ Y, int N) {
    int wave = threadIdx.x >> 6;
    int lane = threadIdx.x & 63;
    int m = lane & 15;
    int quad = lane >> 4;
    const long NT = (long)N >> 4;                  // 16-row tiles
    const long g0 = (long)blockIdx.x * 4 + wave;   // global wave id
    const long gs = (long)gridDim.x * 4;
    if (g0 >= NT) return;

    // Preload all W^T fragments: a-operand for output tile t, k-step kt.
    // Lane (quad,m) holds Wt[(t*16+m)*128 + kt*32 + quad*8 .. +7].
    bf16x8 bfrag[8][4];
    #pragma unroll
    for (int t = 0; t < 8; t++)
        #pragma unroll
        for (int kt = 0; kt < 4; kt++)
            bfrag[t][kt] =
                *(const bf16x8*)(Wt + (t * 16 + m) * 128 + kt * 32 + quad * 8);

    auto loadA = [&](float4* BUF, long tile) {
        const float* ap = X + (tile * 16 + m) * 128 + quad * 8;
        #pragma unroll
        for (int kt = 0; kt < 4; kt++) {
            BUF[2 * kt]     = *(const float4*)(ap + kt * 32);
            BUF[2 * kt + 1] = *(const float4*)(ap + kt * 32 + 4);
        }
    };

    auto compute = [&](const float4* BUF, long tile) {
        long row = tile * 16 + m;
        float dv = dinv[row];
        f32x4 acc[8] = {};
        #pragma unroll
        for (int kt = 0; kt < 4; kt++) {
            float4 lo = BUF[2 * kt], hi = BUF[2 * kt + 1];
            bf16x8 a = {(__bf16)lo.x, (__bf16)lo.y, (__bf16)lo.z, (__bf16)lo.w,
                        (__bf16)hi.x, (__bf16)hi.y, (__bf16)hi.z, (__bf16)hi.w};
            #pragma unroll
            for (int t = 0; t < 8; t++)
                acc[t] = __builtin_amdgcn_mfma_f32_16x16x32_bf16(bfrag[t][kt], a,
                                                                 acc[t], 0, 0, 0);
        }
        // acc[t][r] = out[channel t*16+quad*4+r][row m] -> 8B stores, one row/lane
        __bf16* yp = Y + row * 128 + quad * 4;
        #pragma unroll
        for (int t = 0; t < 8; t++) {
            bf16x4 o;
            #pragma unroll
            for (int r = 0; r < 4; r++) o[r] = (__bf16)(acc[t][r] * dv);
            *(bf16x4*)(yp + t * 16) = o;
        }
    };

    float4 A0[8], A1[8];
    loadA(A0, g0);
    long t = g0;
    while (true) {
        long t1 = t + gs;
        loadA(A1, t1 < NT ? t1 : t);      // clamped dummy prefetch at tail
        compute(A0, t);
        if (t1 >= NT) break;
        long t2 = t1 + gs;
        loadA(A0, t2 < NT ? t2 : t1);
        compute(A1, t1);
        if (t2 >= NT) break;
        t = t2;
    }
}

// ---- fused aggregate + relu + residual + action-weighted readout ------------
// One block per b. 128 thr = 8 node slots x 16 lanes; lane owns 8 channels.
__global__ __launch_bounds__(128) void k_readout(const int* __restrict__ head,
                                                 const int* __restrict__ nxt,
                                                 const int* __restrict__ e_src,
                                                 const float* __restrict__ dinv,
                                                 const __bf16* __restrict__ xws,
                                                 const float* __restrict__ state,
                                                 const float* __restrict__ bgcn,
                                                 const float* __restrict__ action,
                                                 __bf16* __restrict__ xB, int B) {
    __shared__ float red[16][8];
    int b = blockIdx.x;
    int tid = threadIdx.x;
    int lane16 = tid & 15;
    int slot = tid >> 4;       // 0..7
    int c0 = lane16 * 8;
    float4 bg0 = *(const float4*)(bgcn + c0);
    float4 bg1 = *(const float4*)(bgcn + c0 + 4);
    float bg[8] = {bg0.x, bg0.y, bg0.z, bg0.w, bg1.x, bg1.y, bg1.z, bg1.w};
    float acc[8] = {};
    for (int a = slot; a < 10; a += 8) {
        int n = b * 10 + a;
        // sum of pre-scaled rows: self + in-edges (dinv[n] factored out)
        float s[8];
        bf16x8 x = *(const bf16x8*)(xws + (size_t)n * 128 + c0);
        #pragma unroll
        for (int k = 0; k < 8; k++) s[k] = (float)x[k];
        for (int j = head[n]; j >= 0; j = nxt[j]) {
            int sr = e_src[j];
            bf16x8 g = *(const bf16x8*)(xws + (size_t)sr * 128 + c0);
            #pragma unroll
            for (int k = 0; k < 8; k++) s[k] += (float)g[k];
        }
        float di = dinv[n];
        float aw = action[n] * 10.f;
        float4 st0 = *(const float4*)(state + (size_t)n * 128 + c0);
        float4 st1 = *(const float4*)(state + (size_t)n * 128 + c0 + 4);
        float st[8] = {st0.x, st0.y, st0.z, st0.w, st1.x, st1.y, st1.z, st1.w};
        #pragma unroll
        for (int k = 0; k < 8; k++)
            acc[k] += aw * (fmaxf(di * s[k] + bg[k], 0.f) + st[k]);
    }
    // reduce 8 slots -> 1: shuffle over slots within wave, LDS across waves
    #pragma unroll
    for (int k = 0; k < 8; k++) {
        acc[k] += __shfl_down(acc[k], 32);
        acc[k] += __shfl_down(acc[k], 16);
    }
    if (tid >= 64 && tid < 80) {
        #pragma unroll
        for (int k = 0; k < 8; k++) red[tid - 64][k] = acc[k];
    }
    __syncthreads();
    if (tid < 16) {
        bf16x8 o;
        #pragma unroll
        for (int k = 0; k < 8; k++) o[k] = (__bf16)(acc[k] + red[tid][k]);
        *(bf16x8*)(xB + (size_t)b * 128 + c0) = o;
    }
}

// ---- MLP head via MFMA: relu(x@W1+b1) -> relu(@W2+b2) -> @W3+b3 -------------
__global__ __launch_bounds__(256) void k_mlp(const __bf16* __restrict__ xB,
                                             const __bf16* __restrict__ W1t,
                                             const float* __restrict__ b1,
                                             const __bf16* __restrict__ W2t,
                                             const float* __restrict__ b2,
                                             const float* __restrict__ W3,
                                             const float* __restrict__ b3,
                                             float* __restrict__ out, int B) {
    __shared__ __bf16 hs[16][264];
    __shared__ float osum[4][16];
    int wave = threadIdx.x >> 6;
    int lane = threadIdx.x & 63;
    int m = lane & 15;
    int quad = lane >> 4;
    long r0 = (long)blockIdx.x * 16;

    f32x4 acc[4] = {};
    #pragma unroll
    for (int kt = 0; kt < 4; kt++) {
        int k0 = kt * 32 + quad * 8;
        bf16x8 a = *(const bf16x8*)(xB + (r0 + m) * 128 + k0);
        #pragma unroll
        for (int t = 0; t < 4; t++) {
            int n = wave * 64 + t * 16 + m;
            bf16x8 b = *(const bf16x8*)(W1t + (long)n * 128 + k0);
            acc[t] = __builtin_amdgcn_mfma_f32_16x16x32_bf16(a, b, acc[t], 0, 0, 0);
        }
    }
    #pragma unroll
    for (int t = 0; t < 4; t++) {
        int n = wave * 64 + t * 16 + m;
        float bb = b1[n];
        #pragma unroll
        for (int r = 0; r < 4; r++)
            hs[quad * 4 + r][n] = (__bf16)fmaxf(acc[t][r] + bb, 0.f);
    }
    __syncthreads();

    f32x4 acc2[4] = {};
    #pragma unroll
    for (int kt = 0; kt < 8; kt++) {
        int k0 = kt * 32 + quad * 8;
        bf16x8 a = *(const bf16x8*)(&hs[m][k0]);
        #pragma unroll
        for (int t = 0; t < 4; t++) {
            int n = wave * 64 + t * 16 + m;
            bf16x8 b = *(const bf16x8*)(W2t + (long)n * 256 + k0);
            acc2[t] = __builtin_amdgcn_mfma_f32_16x16x32_bf16(a, b, acc2[t], 0, 0, 0);
        }
    }

    float part[4] = {0.f, 0.f, 0.f, 0.f};
    #pragma unroll
    for (int t = 0; t < 4; t++) {
        int n = wave * 64 + t * 16 + m;
        float bb = b2[n], w3 = W3[n];
        #pragma unroll
        for (int r = 0; r < 4; r++)
            part[r] += fmaxf(acc2[t][r] + bb, 0.f) * w3;
    }
    #pragma unroll
    for (int off = 8; off; off >>= 1)
        #pragma unroll
        for (int r = 0; r < 4; r++)
            part[r] += __shfl_down(part[r], off, 16);
    if (m == 0) {
        #pragma unroll
        for (int r = 0; r < 4; r++) osum[wave][quad * 4 + r] = part[r];
    }
    __syncthreads();
    if (threadIdx.x < 16)
        out[r0 + threadIdx.x] = osum[0][threadIdx.x] + osum[1][threadIdx.x] +
                                osum[2][threadIdx.x] + osum[3][threadIdx.x] + b3[0];
}

extern "C" void kernel_launch(void* const* d_in, const int* in_sizes, int n_in,
                              void* d_out, int out_size, void* d_ws, size_t ws_size,
                              hipStream_t stream) {
    const float* state  = (const float*)d_in[0];
    const int*   edge   = (const int*)d_in[1];   // [2, E]: src row then dst row
    const float* action = (const float*)d_in[2];
    const float* W_gcn  = (const float*)d_in[3];
    const float* b_gcn  = (const float*)d_in[4];
    const float* W1     = (const float*)d_in[5];
    const float* b1     = (const float*)d_in[6];
    const float* W2     = (const float*)d_in[7];
    const float* b2     = (const float*)d_in[8];
    const float* W3     = (const float*)d_in[9];
    const float* b3     = (const float*)d_in[10];
    float* out = (float*)d_out;

    int N = in_sizes[0] / 128;
    int E = in_sizes[1] / 2;
    int B = out_size;
    const int* e_src = edge;
    const int* e_dst = edge + E;

    // workspace: xws bf16[N*128] | xB bf16[B*128] | Wgt bf16[128*128]
    //          | W1t bf16[256*128] | W2t bf16[256*256]
    //          | dinv f32[N] | deg i32[N] | head i32[N] | nxt i32[E]
    __bf16* xws = (__bf16*)d_ws;
    __bf16* xB  = xws + (size_t)N * 128;
    __bf16* Wgt = xB + (size_t)B * 128;
    __bf16* W1t = Wgt + 128 * 128;
    __bf16* W2t = W1t + 256 * 128;
    float* dinv = (float*)(W2t + 256 * 256);
    int*   deg  = (int*)(dinv + N);
    int*   head = deg + N;
    int*   nxt  = head + N;

    hipMemsetAsync(deg, 0, (size_t)N * sizeof(int), stream);
    hipMemsetAsync(head, 0xFF, (size_t)N * sizeof(int), stream);  // -1

    k_tconv<<<(128 * 128 + 255) / 256, 256, 0, stream>>>(W_gcn, Wgt, 7, 128 * 128, 128);
    k_tconv<<<(256 * 128 + 255) / 256, 256, 0, stream>>>(W1, W1t, 7, 256 * 128, 256);
    k_tconv<<<(256 * 256 + 255) / 256, 256, 0, stream>>>(W2, W2t, 8, 256 * 256, 256);
    k_edges<<<(E + 255) / 256, 256, 0, stream>>>(e_dst, E, deg, head, nxt);
    k_dinv<<<(N + 255) / 256, 256, 0, stream>>>(deg, dinv, N);
    k_gemm<<<1024, 256, 0, stream>>>(state, Wgt, dinv, xws, N);
    k_readout<<<B, 128, 0, stream>>>(head, nxt, e_src, dinv, xws, state, b_gcn,
                                     action, xB, B);
    k_mlp<<<B / 16, 256, 0, stream>>>(xB, W1t, b1, W2t, b2, W3, b3, out, B);
}

// Round 3
// 635.060 us; speedup vs baseline: 1.1063x; 1.0212x over previous
//
#include <hip/hip_runtime.h>

// Sizes: N=500000, C=128, H=256, A=10, E=600000, B=50000.
// R6: k_gemm reg-resident W^T + double-buffered A + swapped MFMA operands
//     (latency-bound 177 -> ~123us by subtraction).
// R7 (this round):
//   - k_gemm epilogue: in-wave LDS transpose (padded 136) -> 4x 1KB coalesced
//     row stores (was 8x 8B stores = 16x32B scatter/instr, <=50% write eff).
//     No __syncthreads (waves are desynced in grid-stride loop); same-wave DS
//     ordering + explicit lgkmcnt(0)+sched_barrier before readback.
//   - graph: linked list -> CSR (count+slot, 3-kernel scan, scatter) to kill
//     the head->nxt dependent-latency chain in readout.
//   - k_readout: 256 thr, 8 b's/block, slot-pair per b, exactly 5 nodes/slot
//     (no divergent second pass), contiguous srcs with +1 prefetch, LDS
//     pairwise reduction, coalesced 8B xB stores.

typedef __bf16 bf16x8 __attribute__((ext_vector_type(8)));
typedef __bf16 bf16x4 __attribute__((ext_vector_type(4)));
typedef float f32x4 __attribute__((ext_vector_type(4)));

// ---- per-edge: in-degree count + per-edge slot (for CSR scatter) ------------
__global__ __launch_bounds__(256) void k_edges(const int* __restrict__ dst, int E,
                                               int* __restrict__ deg,
                                               int* __restrict__ slot) {
    int e = blockIdx.x * 256 + threadIdx.x;
    if (e < E) slot[e] = atomicAdd(&deg[dst[e]], 1);
}

// ---- dinv = rsqrt(deg + 1)  (+1 = self loop) --------------------------------
__global__ __launch_bounds__(256) void k_dinv(const int* __restrict__ deg,
                                              float* __restrict__ dinv, int N) {
    int i = blockIdx.x * 256 + threadIdx.x;
    if (i < N) dinv[i] = rsqrtf((float)deg[i] + 1.0f);
}

// ---- 3-kernel exclusive scan of deg -> off ----------------------------------
__global__ __launch_bounds__(256) void k_scan1(const int* __restrict__ deg,
                                               int* __restrict__ off,
                                               int* __restrict__ bsum, int N) {
    __shared__ int tmp[256];
    int tid = threadIdx.x;
    int i0 = blockIdx.x * 1024 + tid * 4;
    int4 v = {0, 0, 0, 0};
    if (i0 + 3 < N) v = *(const int4*)(deg + i0);
    else {
        if (i0 < N)     v.x = deg[i0];
        if (i0 + 1 < N) v.y = deg[i0 + 1];
        if (i0 + 2 < N) v.z = deg[i0 + 2];
        if (i0 + 3 < N) v.w = deg[i0 + 3];
    }
    int s = v.x + v.y + v.z + v.w;
    tmp[tid] = s;
    __syncthreads();
    for (int d = 1; d < 256; d <<= 1) {
        int t = (tid >= d) ? tmp[tid - d] : 0;
        __syncthreads();
        tmp[tid] += t;
        __syncthreads();
    }
    int excl = tmp[tid] - s;
    int o0 = excl, o1 = o0 + v.x, o2 = o1 + v.y, o3 = o2 + v.z;
    if (i0 + 3 < N) {
        int4 o = {o0, o1, o2, o3};
        *(int4*)(off + i0) = o;
    } else {
        if (i0 < N)     off[i0] = o0;
        if (i0 + 1 < N) off[i0 + 1] = o1;
        if (i0 + 2 < N) off[i0 + 2] = o2;
        if (i0 + 3 < N) off[i0 + 3] = o3;
    }
    if (tid == 255) bsum[blockIdx.x] = tmp[255];
}

__global__ __launch_bounds__(512) void k_scan2(int* __restrict__ bsum, int nb) {
    __shared__ int tmp[512];
    int tid = threadIdx.x;
    int v = (tid < nb) ? bsum[tid] : 0;
    tmp[tid] = v;
    __syncthreads();
    for (int d = 1; d < 512; d <<= 1) {
        int t = (tid >= d) ? tmp[tid - d] : 0;
        __syncthreads();
        tmp[tid] += t;
        __syncthreads();
    }
    if (tid < nb) bsum[tid] = tmp[tid] - v;   // exclusive block offsets
}

__global__ __launch_bounds__(256) void k_scan3(int* __restrict__ off,
                                               const int* __restrict__ bsum,
                                               int N, int E) {
    int i0 = blockIdx.x * 1024 + threadIdx.x * 4;
    int add = bsum[blockIdx.x];
    if (i0 + 3 < N) {
        int4 v = *(int4*)(off + i0);
        v.x += add; v.y += add; v.z += add; v.w += add;
        *(int4*)(off + i0) = v;
    } else {
        if (i0 < N)     off[i0] += add;
        if (i0 + 1 < N) off[i0 + 1] += add;
        if (i0 + 2 < N) off[i0 + 2] += add;
        if (i0 + 3 < N) off[i0 + 3] += add;
    }
    if (blockIdx.x == 0 && threadIdx.x == 0) off[N] = E;
}

// ---- scatter edges into CSR order -------------------------------------------
__global__ __launch_bounds__(256) void k_scatter(const int* __restrict__ dst,
                                                 const int* __restrict__ src,
                                                 const int* __restrict__ slot,
                                                 const int* __restrict__ off,
                                                 int* __restrict__ srcs, int E) {
    int e = blockIdx.x * 256 + threadIdx.x;
    if (e < E) srcs[off[dst[e]] + slot[e]] = src[e];
}

// ---- transpose-convert weights: Wt[n*K+k] = bf16(W[k*Nc+n]) -----------------
__global__ __launch_bounds__(256) void k_tconv(const float* __restrict__ W,
                                               __bf16* __restrict__ Wt,
                                               int kbits, int total, int Nc) {
    int i = blockIdx.x * 256 + threadIdx.x;
    if (i < total) {
        int n = i >> kbits;
        int k = i & ((1 << kbits) - 1);
        Wt[i] = (__bf16)W[(long)k * Nc + n];
    }
}

// ---- xws = bf16( dinv[row] * (state @ W_gcn) )  via MFMA 16x16x32 bf16 ------
__global__ __launch_bounds__(256, 2) void k_gemm(const float* __restrict__ X,
                                                 const __bf16* __restrict__ Wt,
                                                 const float* __restrict__ dinv,
                                                 __bf16* __restrict__ Y, int N) {
    __shared__ __bf16 st[4][16][136];   // per-wave transpose staging, +8 pad
    int wave = threadIdx.x >> 6;
    int lane = threadIdx.x & 63;
    int m = lane & 15;
    int quad = lane >> 4;
    const long NT = (long)N >> 4;                  // 16-row tiles
    const long g0 = (long)blockIdx.x * 4 + wave;   // global wave id
    const long gs = (long)gridDim.x * 4;
    if (g0 >= NT) return;

    // W^T fragments resident for the whole kernel (128 VGPRs).
    bf16x8 bfrag[8][4];
    #pragma unroll
    for (int t = 0; t < 8; t++)
        #pragma unroll
        for (int kt = 0; kt < 4; kt++)
            bfrag[t][kt] =
                *(const bf16x8*)(Wt + (t * 16 + m) * 128 + kt * 32 + quad * 8);

    auto loadA = [&](float4* BUF, long tile) {
        const float* ap = X + (tile * 16 + m) * 128 + quad * 8;
        #pragma unroll
        for (int kt = 0; kt < 4; kt++) {
            BUF[2 * kt]     = *(const float4*)(ap + kt * 32);
            BUF[2 * kt + 1] = *(const float4*)(ap + kt * 32 + 4);
        }
    };

    auto compute = [&](const float4* BUF, long tile) {
        long row = tile * 16 + m;
        float dv = dinv[row];
        f32x4 acc[8] = {};
        #pragma unroll
        for (int kt = 0; kt < 4; kt++) {
            float4 lo = BUF[2 * kt], hi = BUF[2 * kt + 1];
            bf16x8 a = {(__bf16)lo.x, (__bf16)lo.y, (__bf16)lo.z, (__bf16)lo.w,
                        (__bf16)hi.x, (__bf16)hi.y, (__bf16)hi.z, (__bf16)hi.w};
            #pragma unroll
            for (int t = 0; t < 8; t++)
                acc[t] = __builtin_amdgcn_mfma_f32_16x16x32_bf16(bfrag[t][kt], a,
                                                                 acc[t], 0, 0, 0);
        }
        // stage lane-owned row m into LDS, then read back row-major and store
        // 4 rows x 256B = 1KB fully-coalesced per instruction.
        #pragma unroll
        for (int t = 0; t < 8; t++) {
            bf16x4 o;
            #pragma unroll
            for (int r = 0; r < 4; r++) o[r] = (__bf16)(acc[t][r] * dv);
            *(bf16x4*)&st[wave][m][t * 16 + quad * 4] = o;
        }
        asm volatile("s_waitcnt lgkmcnt(0)" ::: "memory");
        __builtin_amdgcn_sched_barrier(0);
        #pragma unroll
        for (int it = 0; it < 4; it++) {
            bf16x8 v = *(const bf16x8*)&st[wave][it * 4 + quad][m * 8];
            *(bf16x8*)(Y + (tile * 16 + it * 4 + quad) * 128 + m * 8) = v;
        }
    };

    float4 A0[8], A1[8];
    loadA(A0, g0);
    long t = g0;
    while (true) {
        long t1 = t + gs;
        loadA(A1, t1 < NT ? t1 : t);      // clamped dummy prefetch at tail
        compute(A0, t);
        if (t1 >= NT) break;
        long t2 = t1 + gs;
        loadA(A0, t2 < NT ? t2 : t1);
        compute(A1, t1);
        if (t2 >= NT) break;
        t = t2;
    }
}

// ---- fused aggregate + relu + residual + action-weighted readout ------------
// 256 thr = 16 slots x 16 lanes. Block handles 8 b's; slot pair (2s,2s+1)
// covers b_local = s: slot handles nodes b*10 + (slot&1)*5 + k, k<5.
__global__ __launch_bounds__(256) void k_readout(const int* __restrict__ off,
                                                 const int* __restrict__ srcs,
                                                 const float* __restrict__ dinv,
                                                 const __bf16* __restrict__ xws,
                                                 const float* __restrict__ state,
                                                 const float* __restrict__ bgcn,
                                                 const float* __restrict__ action,
                                                 __bf16* __restrict__ xB, int B) {
    __shared__ float red[16][132];
    int tid = threadIdx.x;
    int slot = tid >> 4;
    int lane16 = tid & 15;
    int c0 = lane16 * 8;
    int b = blockIdx.x * 8 + (slot >> 1);

    float4 bg0 = *(const float4*)(bgcn + c0);
    float4 bg1 = *(const float4*)(bgcn + c0 + 4);
    float bg[8] = {bg0.x, bg0.y, bg0.z, bg0.w, bg1.x, bg1.y, bg1.z, bg1.w};
    float acc[8] = {};

    if (b < B) {
        int nbase = b * 10 + (slot & 1) * 5;
        for (int k = 0; k < 5; k++) {
            int n = nbase + k;
            int o0 = off[n], o1 = off[n + 1];
            bf16x8 x = *(const bf16x8*)(xws + (size_t)n * 128 + c0);
            float s[8];
            #pragma unroll
            for (int i = 0; i < 8; i++) s[i] = (float)x[i];
            // CSR edge loop, +1-ahead src prefetch (independent gathers)
            int j = o0;
            int sr = (j < o1) ? srcs[j] : 0;
            while (j < o1) {
                bf16x8 g = *(const bf16x8*)(xws + (size_t)sr * 128 + c0);
                ++j;
                int srn = (j < o1) ? srcs[j] : 0;
                #pragma unroll
                for (int i = 0; i < 8; i++) s[i] += (float)g[i];
                sr = srn;
            }
            float di = dinv[n];
            float aw = action[n] * 10.f;
            float4 st0 = *(const float4*)(state + (size_t)n * 128 + c0);
            float4 st1 = *(const float4*)(state + (size_t)n * 128 + c0 + 4);
            float stv[8] = {st0.x, st0.y, st0.z, st0.w,
                            st1.x, st1.y, st1.z, st1.w};
            #pragma unroll
            for (int i = 0; i < 8; i++)
                acc[i] += aw * (fmaxf(di * s[i] + bg[i], 0.f) + stv[i]);
        }
    }
    f32x4 va = {acc[0], acc[1], acc[2], acc[3]};
    f32x4 vb = {acc[4], acc[5], acc[6], acc[7]};
    *(f32x4*)&red[slot][c0] = va;
    *(f32x4*)&red[slot][c0 + 4] = vb;
    __syncthreads();
    // 8 b x 128 ch outputs; thread t: b_local = t>>5, 4 consecutive channels
    int bl = tid >> 5;
    int ch0 = (tid & 31) * 4;
    int b2 = blockIdx.x * 8 + bl;
    if (b2 < B) {
        bf16x4 o;
        #pragma unroll
        for (int c = 0; c < 4; c++)
            o[c] = (__bf16)(red[2 * bl][ch0 + c] + red[2 * bl + 1][ch0 + c]);
        *(bf16x4*)(xB + (size_t)b2 * 128 + ch0) = o;
    }
}

// ---- MLP head via MFMA: relu(x@W1+b1) -> relu(@W2+b2) -> @W3+b3 -------------
__global__ __launch_bounds__(256) void k_mlp(const __bf16* __restrict__ xB,
                                             const __bf16* __restrict__ W1t,
                                             const float* __restrict__ b1,
                                             const __bf16* __restrict__ W2t,
                                             const float* __restrict__ b2,
                                             const float* __restrict__ W3,
                                             const float* __restrict__ b3,
                                             float* __restrict__ out, int B) {
    __shared__ __bf16 hs[16][264];
    __shared__ float osum[4][16];
    int wave = threadIdx.x >> 6;
    int lane = threadIdx.x & 63;
    int m = lane & 15;
    int quad = lane >> 4;
    long r0 = (long)blockIdx.x * 16;

    f32x4 acc[4] = {};
    #pragma unroll
    for (int kt = 0; kt < 4; kt++) {
        int k0 = kt * 32 + quad * 8;
        bf16x8 a = *(const bf16x8*)(xB + (r0 + m) * 128 + k0);
        #pragma unroll
        for (int t = 0; t < 4; t++) {
            int n = wave * 64 + t * 16 + m;
            bf16x8 b = *(const bf16x8*)(W1t + (long)n * 128 + k0);
            acc[t] = __builtin_amdgcn_mfma_f32_16x16x32_bf16(a, b, acc[t], 0, 0, 0);
        }
    }
    #pragma unroll
    for (int t = 0; t < 4; t++) {
        int n = wave * 64 + t * 16 + m;
        float bb = b1[n];
        #pragma unroll
        for (int r = 0; r < 4; r++)
            hs[quad * 4 + r][n] = (__bf16)fmaxf(acc[t][r] + bb, 0.f);
    }
    __syncthreads();

    f32x4 acc2[4] = {};
    #pragma unroll
    for (int kt = 0; kt < 8; kt++) {
        int k0 = kt * 32 + quad * 8;
        bf16x8 a = *(const bf16x8*)(&hs[m][k0]);
        #pragma unroll
        for (int t = 0; t < 4; t++) {
            int n = wave * 64 + t * 16 + m;
            bf16x8 b = *(const bf16x8*)(W2t + (long)n * 256 + k0);
            acc2[t] = __builtin_amdgcn_mfma_f32_16x16x32_bf16(a, b, acc2[t], 0, 0, 0);
        }
    }

    float part[4] = {0.f, 0.f, 0.f, 0.f};
    #pragma unroll
    for (int t = 0; t < 4; t++) {
        int n = wave * 64 + t * 16 + m;
        float bb = b2[n], w3 = W3[n];
        #pragma unroll
        for (int r = 0; r < 4; r++)
            part[r] += fmaxf(acc2[t][r] + bb, 0.f) * w3;
    }
    #pragma unroll
    for (int off = 8; off; off >>= 1)
        #pragma unroll
        for (int r = 0; r < 4; r++)
            part[r] += __shfl_down(part[r], off, 16);
    if (m == 0) {
        #pragma unroll
        for (int r = 0; r < 4; r++) osum[wave][quad * 4 + r] = part[r];
    }
    __syncthreads();
    if (threadIdx.x < 16)
        out[r0 + threadIdx.x] = osum[0][threadIdx.x] + osum[1][threadIdx.x] +
                                osum[2][threadIdx.x] + osum[3][threadIdx.x] + b3[0];
}

extern "C" void kernel_launch(void* const* d_in, const int* in_sizes, int n_in,
                              void* d_out, int out_size, void* d_ws, size_t ws_size,
                              hipStream_t stream) {
    const float* state  = (const float*)d_in[0];
    const int*   edge   = (const int*)d_in[1];   // [2, E]: src row then dst row
    const float* action = (const float*)d_in[2];
    const float* W_gcn  = (const float*)d_in[3];
    const float* b_gcn  = (const float*)d_in[4];
    const float* W1     = (const float*)d_in[5];
    const float* b1     = (const float*)d_in[6];
    const float* W2     = (const float*)d_in[7];
    const float* b2     = (const float*)d_in[8];
    const float* W3     = (const float*)d_in[9];
    const float* b3     = (const float*)d_in[10];
    float* out = (float*)d_out;

    int N = in_sizes[0] / 128;
    int E = in_sizes[1] / 2;
    int B = out_size;
    const int* e_src = edge;
    const int* e_dst = edge + E;

    // workspace layout (all 16B-aligned for the given sizes):
    // xws bf16[N*128] | xB bf16[B*128] | Wgt bf16[128*128] | W1t bf16[256*128]
    // | W2t bf16[256*256] | dinv f32[N] | deg i32[N] | off i32[N+4]
    // | slot i32[E] | srcs i32[E] | bsum i32[512]
    __bf16* xws = (__bf16*)d_ws;
    __bf16* xB  = xws + (size_t)N * 128;
    __bf16* Wgt = xB + (size_t)B * 128;
    __bf16* W1t = Wgt + 128 * 128;
    __bf16* W2t = W1t + 256 * 128;
    float* dinv = (float*)(W2t + 256 * 256);
    int*   deg  = (int*)(dinv + N);
    int*   off  = deg + N;
    int*   slot = off + (N + 4);
    int*   srcs = slot + E;
    int*   bsum = srcs + E;

    int NB = (N + 1023) / 1024;   // scan blocks (489 <= 512)

    hipMemsetAsync(deg, 0, (size_t)N * sizeof(int), stream);

    k_tconv<<<(128 * 128 + 255) / 256, 256, 0, stream>>>(W_gcn, Wgt, 7, 128 * 128, 128);
    k_tconv<<<(256 * 128 + 255) / 256, 256, 0, stream>>>(W1, W1t, 7, 256 * 128, 256);
    k_tconv<<<(256 * 256 + 255) / 256, 256, 0, stream>>>(W2, W2t, 8, 256 * 256, 256);
    k_edges<<<(E + 255) / 256, 256, 0, stream>>>(e_dst, E, deg, slot);
    k_scan1<<<NB, 256, 0, stream>>>(deg, off, bsum, N);
    k_scan2<<<1, 512, 0, stream>>>(bsum, NB);
    k_scan3<<<NB, 256, 0, stream>>>(off, bsum, N, E);
    k_dinv<<<(N + 255) / 256, 256, 0, stream>>>(deg, dinv, N);
    k_scatter<<<(E + 255) / 256, 256, 0, stream>>>(e_dst, e_src, slot, off, srcs, E);
    k_gemm<<<1024, 256, 0, stream>>>(state, Wgt, dinv, xws, N);
    k_readout<<<(B + 7) / 8, 256, 0, stream>>>(off, srcs, dinv, xws, state, b_gcn,
                                               action, xB, B);
    k_mlp<<<B / 16, 256, 0, stream>>>(xB, W1t, b1, W2t, b2, W3, b3, out, B);
}

// Round 4
// 634.006 us; speedup vs baseline: 1.1081x; 1.0017x over previous
//
#include <hip/hip_runtime.h>

// Sizes: N=500000, C=128, H=256, A=10, E=600000, B=50000.
// R6: k_gemm reg-resident W^T + double-buffered A + swapped MFMA operands.
// R7: LDS-transpose gemm epilogue (coalesced 1KB stores); CSR graph; readout
//     restructure (16 slots x 16 lanes, 5 nodes/slot, prefetched gathers).
// R8 (this round): ONE change — k_gemm __launch_bounds__(256,2) -> (256,1).
//   Theory: reg demand ~244 (bfrag 128 + A0/A1 64 + acc 32 + addr) exceeded
//   the 256-cap imposed by min-2-waves/EU -> scratch spill per tile, which
//   serializes like R1's latency chain (R1 model closes at 45K cy/tile/wave).
//   With min-1-wave/EU the allocator gets 512 regs, ~244 used -> no spill;
//   HW still fits 2 waves/SIMD (2 x 256 = 512 unified VGPRs).

typedef __bf16 bf16x8 __attribute__((ext_vector_type(8)));
typedef __bf16 bf16x4 __attribute__((ext_vector_type(4)));
typedef float f32x4 __attribute__((ext_vector_type(4)));

// ---- per-edge: in-degree count + per-edge slot (for CSR scatter) ------------
__global__ __launch_bounds__(256) void k_edges(const int* __restrict__ dst, int E,
                                               int* __restrict__ deg,
                                               int* __restrict__ slot) {
    int e = blockIdx.x * 256 + threadIdx.x;
    if (e < E) slot[e] = atomicAdd(&deg[dst[e]], 1);
}

// ---- dinv = rsqrt(deg + 1)  (+1 = self loop) --------------------------------
__global__ __launch_bounds__(256) void k_dinv(const int* __restrict__ deg,
                                              float* __restrict__ dinv, int N) {
    int i = blockIdx.x * 256 + threadIdx.x;
    if (i < N) dinv[i] = rsqrtf((float)deg[i] + 1.0f);
}

// ---- 3-kernel exclusive scan of deg -> off ----------------------------------
__global__ __launch_bounds__(256) void k_scan1(const int* __restrict__ deg,
                                               int* __restrict__ off,
                                               int* __restrict__ bsum, int N) {
    __shared__ int tmp[256];
    int tid = threadIdx.x;
    int i0 = blockIdx.x * 1024 + tid * 4;
    int4 v = {0, 0, 0, 0};
    if (i0 + 3 < N) v = *(const int4*)(deg + i0);
    else {
        if (i0 < N)     v.x = deg[i0];
        if (i0 + 1 < N) v.y = deg[i0 + 1];
        if (i0 + 2 < N) v.z = deg[i0 + 2];
        if (i0 + 3 < N) v.w = deg[i0 + 3];
    }
    int s = v.x + v.y + v.z + v.w;
    tmp[tid] = s;
    __syncthreads();
    for (int d = 1; d < 256; d <<= 1) {
        int t = (tid >= d) ? tmp[tid - d] : 0;
        __syncthreads();
        tmp[tid] += t;
        __syncthreads();
    }
    int excl = tmp[tid] - s;
    int o0 = excl, o1 = o0 + v.x, o2 = o1 + v.y, o3 = o2 + v.z;
    if (i0 + 3 < N) {
        int4 o = {o0, o1, o2, o3};
        *(int4*)(off + i0) = o;
    } else {
        if (i0 < N)     off[i0] = o0;
        if (i0 + 1 < N) off[i0 + 1] = o1;
        if (i0 + 2 < N) off[i0 + 2] = o2;
        if (i0 + 3 < N) off[i0 + 3] = o3;
    }
    if (tid == 255) bsum[blockIdx.x] = tmp[255];
}

__global__ __launch_bounds__(512) void k_scan2(int* __restrict__ bsum, int nb) {
    __shared__ int tmp[512];
    int tid = threadIdx.x;
    int v = (tid < nb) ? bsum[tid] : 0;
    tmp[tid] = v;
    __syncthreads();
    for (int d = 1; d < 512; d <<= 1) {
        int t = (tid >= d) ? tmp[tid - d] : 0;
        __syncthreads();
        tmp[tid] += t;
        __syncthreads();
    }
    if (tid < nb) bsum[tid] = tmp[tid] - v;   // exclusive block offsets
}

__global__ __launch_bounds__(256) void k_scan3(int* __restrict__ off,
                                               const int* __restrict__ bsum,
                                               int N, int E) {
    int i0 = blockIdx.x * 1024 + threadIdx.x * 4;
    int add = bsum[blockIdx.x];
    if (i0 + 3 < N) {
        int4 v = *(int4*)(off + i0);
        v.x += add; v.y += add; v.z += add; v.w += add;
        *(int4*)(off + i0) = v;
    } else {
        if (i0 < N)     off[i0] += add;
        if (i0 + 1 < N) off[i0 + 1] += add;
        if (i0 + 2 < N) off[i0 + 2] += add;
        if (i0 + 3 < N) off[i0 + 3] += add;
    }
    if (blockIdx.x == 0 && threadIdx.x == 0) off[N] = E;
}

// ---- scatter edges into CSR order -------------------------------------------
__global__ __launch_bounds__(256) void k_scatter(const int* __restrict__ dst,
                                                 const int* __restrict__ src,
                                                 const int* __restrict__ slot,
                                                 const int* __restrict__ off,
                                                 int* __restrict__ srcs, int E) {
    int e = blockIdx.x * 256 + threadIdx.x;
    if (e < E) srcs[off[dst[e]] + slot[e]] = src[e];
}

// ---- transpose-convert weights: Wt[n*K+k] = bf16(W[k*Nc+n]) -----------------
__global__ __launch_bounds__(256) void k_tconv(const float* __restrict__ W,
                                               __bf16* __restrict__ Wt,
                                               int kbits, int total, int Nc) {
    int i = blockIdx.x * 256 + threadIdx.x;
    if (i < total) {
        int n = i >> kbits;
        int k = i & ((1 << kbits) - 1);
        Wt[i] = (__bf16)W[(long)k * Nc + n];
    }
}

// ---- xws = bf16( dinv[row] * (state @ W_gcn) )  via MFMA 16x16x32 bf16 ------
__global__ __launch_bounds__(256, 1) void k_gemm(const float* __restrict__ X,
                                                 const __bf16* __restrict__ Wt,
                                                 const float* __restrict__ dinv,
                                                 __bf16* __restrict__ Y, int N) {
    __shared__ __bf16 st[4][16][136];   // per-wave transpose staging, +8 pad
    int wave = threadIdx.x >> 6;
    int lane = threadIdx.x & 63;
    int m = lane & 15;
    int quad = lane >> 4;
    const long NT = (long)N >> 4;                  // 16-row tiles
    const long g0 = (long)blockIdx.x * 4 + wave;   // global wave id
    const long gs = (long)gridDim.x * 4;
    if (g0 >= NT) return;

    // W^T fragments resident for the whole kernel (128 VGPRs).
    bf16x8 bfrag[8][4];
    #pragma unroll
    for (int t = 0; t < 8; t++)
        #pragma unroll
        for (int kt = 0; kt < 4; kt++)
            bfrag[t][kt] =
                *(const bf16x8*)(Wt + (t * 16 + m) * 128 + kt * 32 + quad * 8);

    auto loadA = [&](float4* BUF, long tile) {
        const float* ap = X + (tile * 16 + m) * 128 + quad * 8;
        #pragma unroll
        for (int kt = 0; kt < 4; kt++) {
            BUF[2 * kt]     = *(const float4*)(ap + kt * 32);
            BUF[2 * kt + 1] = *(const float4*)(ap + kt * 32 + 4);
        }
    };

    auto compute = [&](const float4* BUF, long tile) {
        long row = tile * 16 + m;
        float dv = dinv[row];
        f32x4 acc[8] = {};
        #pragma unroll
        for (int kt = 0; kt < 4; kt++) {
            float4 lo = BUF[2 * kt], hi = BUF[2 * kt + 1];
            bf16x8 a = {(__bf16)lo.x, (__bf16)lo.y, (__bf16)lo.z, (__bf16)lo.w,
                        (__bf16)hi.x, (__bf16)hi.y, (__bf16)hi.z, (__bf16)hi.w};
            #pragma unroll
            for (int t = 0; t < 8; t++)
                acc[t] = __builtin_amdgcn_mfma_f32_16x16x32_bf16(bfrag[t][kt], a,
                                                                 acc[t], 0, 0, 0);
        }
        // stage lane-owned row m into LDS, then read back row-major and store
        // 4 rows x 256B = 1KB fully-coalesced per instruction.
        #pragma unroll
        for (int t = 0; t < 8; t++) {
            bf16x4 o;
            #pragma unroll
            for (int r = 0; r < 4; r++) o[r] = (__bf16)(acc[t][r] * dv);
            *(bf16x4*)&st[wave][m][t * 16 + quad * 4] = o;
        }
        asm volatile("s_waitcnt lgkmcnt(0)" ::: "memory");
        __builtin_amdgcn_sched_barrier(0);
        #pragma unroll
        for (int it = 0; it < 4; it++) {
            bf16x8 v = *(const bf16x8*)&st[wave][it * 4 + quad][m * 8];
            *(bf16x8*)(Y + (tile * 16 + it * 4 + quad) * 128 + m * 8) = v;
        }
    };

    float4 A0[8], A1[8];
    loadA(A0, g0);
    long t = g0;
    while (true) {
        long t1 = t + gs;
        loadA(A1, t1 < NT ? t1 : t);      // clamped dummy prefetch at tail
        compute(A0, t);
        if (t1 >= NT) break;
        long t2 = t1 + gs;
        loadA(A0, t2 < NT ? t2 : t1);
        compute(A1, t1);
        if (t2 >= NT) break;
        t = t2;
    }
}

// ---- fused aggregate + relu + residual + action-weighted readout ------------
// 256 thr = 16 slots x 16 lanes. Block handles 8 b's; slot pair (2s,2s+1)
// covers b_local = s: slot handles nodes b*10 + (slot&1)*5 + k, k<5.
__global__ __launch_bounds__(256) void k_readout(const int* __restrict__ off,
                                                 const int* __restrict__ srcs,
                                                 const float* __restrict__ dinv,
                                                 const __bf16* __restrict__ xws,
                                                 const float* __restrict__ state,
                                                 const float* __restrict__ bgcn,
                                                 const float* __restrict__ action,
                                                 __bf16* __restrict__ xB, int B) {
    __shared__ float red[16][132];
    int tid = threadIdx.x;
    int slot = tid >> 4;
    int lane16 = tid & 15;
    int c0 = lane16 * 8;
    int b = blockIdx.x * 8 + (slot >> 1);

    float4 bg0 = *(const float4*)(bgcn + c0);
    float4 bg1 = *(const float4*)(bgcn + c0 + 4);
    float bg[8] = {bg0.x, bg0.y, bg0.z, bg0.w, bg1.x, bg1.y, bg1.z, bg1.w};
    float acc[8] = {};

    if (b < B) {
        int nbase = b * 10 + (slot & 1) * 5;
        for (int k = 0; k < 5; k++) {
            int n = nbase + k;
            int o0 = off[n], o1 = off[n + 1];
            bf16x8 x = *(const bf16x8*)(xws + (size_t)n * 128 + c0);
            float s[8];
            #pragma unroll
            for (int i = 0; i < 8; i++) s[i] = (float)x[i];
            // CSR edge loop, +1-ahead src prefetch (independent gathers)
            int j = o0;
            int sr = (j < o1) ? srcs[j] : 0;
            while (j < o1) {
                bf16x8 g = *(const bf16x8*)(xws + (size_t)sr * 128 + c0);
                ++j;
                int srn = (j < o1) ? srcs[j] : 0;
                #pragma unroll
                for (int i = 0; i < 8; i++) s[i] += (float)g[i];
                sr = srn;
            }
            float di = dinv[n];
            float aw = action[n] * 10.f;
            float4 st0 = *(const float4*)(state + (size_t)n * 128 + c0);
            float4 st1 = *(const float4*)(state + (size_t)n * 128 + c0 + 4);
            float stv[8] = {st0.x, st0.y, st0.z, st0.w,
                            st1.x, st1.y, st1.z, st1.w};
            #pragma unroll
            for (int i = 0; i < 8; i++)
                acc[i] += aw * (fmaxf(di * s[i] + bg[i], 0.f) + stv[i]);
        }
    }
    f32x4 va = {acc[0], acc[1], acc[2], acc[3]};
    f32x4 vb = {acc[4], acc[5], acc[6], acc[7]};
    *(f32x4*)&red[slot][c0] = va;
    *(f32x4*)&red[slot][c0 + 4] = vb;
    __syncthreads();
    // 8 b x 128 ch outputs; thread t: b_local = t>>5, 4 consecutive channels
    int bl = tid >> 5;
    int ch0 = (tid & 31) * 4;
    int b2 = blockIdx.x * 8 + bl;
    if (b2 < B) {
        bf16x4 o;
        #pragma unroll
        for (int c = 0; c < 4; c++)
            o[c] = (__bf16)(red[2 * bl][ch0 + c] + red[2 * bl + 1][ch0 + c]);
        *(bf16x4*)(xB + (size_t)b2 * 128 + ch0) = o;
    }
}

// ---- MLP head via MFMA: relu(x@W1+b1) -> relu(@W2+b2) -> @W3+b3 -------------
__global__ __launch_bounds__(256) void k_mlp(const __bf16* __restrict__ xB,
                                             const __bf16* __restrict__ W1t,
                                             const float* __restrict__ b1,
                                             const __bf16* __restrict__ W2t,
                                             const float* __restrict__ b2,
                                             const float* __restrict__ W3,
                                             const float* __restrict__ b3,
                                             float* __restrict__ out, int B) {
    __shared__ __bf16 hs[16][264];
    __shared__ float osum[4][16];
    int wave = threadIdx.x >> 6;
    int lane = threadIdx.x & 63;
    int m = lane & 15;
    int quad = lane >> 4;
    long r0 = (long)blockIdx.x * 16;

    f32x4 acc[4] = {};
    #pragma unroll
    for (int kt = 0; kt < 4; kt++) {
        int k0 = kt * 32 + quad * 8;
        bf16x8 a = *(const bf16x8*)(xB + (r0 + m) * 128 + k0);
        #pragma unroll
        for (int t = 0; t < 4; t++) {
            int n = wave * 64 + t * 16 + m;
            bf16x8 b = *(const bf16x8*)(W1t + (long)n * 128 + k0);
            acc[t] = __builtin_amdgcn_mfma_f32_16x16x32_bf16(a, b, acc[t], 0, 0, 0);
        }
    }
    #pragma unroll
    for (int t = 0; t < 4; t++) {
        int n = wave * 64 + t * 16 + m;
        float bb = b1[n];
        #pragma unroll
        for (int r = 0; r < 4; r++)
            hs[quad * 4 + r][n] = (__bf16)fmaxf(acc[t][r] + bb, 0.f);
    }
    __syncthreads();

    f32x4 acc2[4] = {};
    #pragma unroll
    for (int kt = 0; kt < 8; kt++) {
        int k0 = kt * 32 + quad * 8;
        bf16x8 a = *(const bf16x8*)(&hs[m][k0]);
        #pragma unroll
        for (int t = 0; t < 4; t++) {
            int n = wave * 64 + t * 16 + m;
            bf16x8 b = *(const bf16x8*)(W2t + (long)n * 256 + k0);
            acc2[t] = __builtin_amdgcn_mfma_f32_16x16x32_bf16(a, b, acc2[t], 0, 0, 0);
        }
    }

    float part[4] = {0.f, 0.f, 0.f, 0.f};
    #pragma unroll
    for (int t = 0; t < 4; t++) {
        int n = wave * 64 + t * 16 + m;
        float bb = b2[n], w3 = W3[n];
        #pragma unroll
        for (int r = 0; r < 4; r++)
            part[r] += fmaxf(acc2[t][r] + bb, 0.f) * w3;
    }
    #pragma unroll
    for (int off = 8; off; off >>= 1)
        #pragma unroll
        for (int r = 0; r < 4; r++)
            part[r] += __shfl_down(part[r], off, 16);
    if (m == 0) {
        #pragma unroll
        for (int r = 0; r < 4; r++) osum[wave][quad * 4 + r] = part[r];
    }
    __syncthreads();
    if (threadIdx.x < 16)
        out[r0 + threadIdx.x] = osum[0][threadIdx.x] + osum[1][threadIdx.x] +
                                osum[2][threadIdx.x] + osum[3][threadIdx.x] + b3[0];
}

extern "C" void kernel_launch(void* const* d_in, const int* in_sizes, int n_in,
                              void* d_out, int out_size, void* d_ws, size_t ws_size,
                              hipStream_t stream) {
    const float* state  = (const float*)d_in[0];
    const int*   edge   = (const int*)d_in[1];   // [2, E]: src row then dst row
    const float* action = (const float*)d_in[2];
    const float* W_gcn  = (const float*)d_in[3];
    const float* b_gcn  = (const float*)d_in[4];
    const float* W1     = (const float*)d_in[5];
    const float* b1     = (const float*)d_in[6];
    const float* W2     = (const float*)d_in[7];
    const float* b2     = (const float*)d_in[8];
    const float* W3     = (const float*)d_in[9];
    const float* b3     = (const float*)d_in[10];
    float* out = (float*)d_out;

    int N = in_sizes[0] / 128;
    int E = in_sizes[1] / 2;
    int B = out_size;
    const int* e_src = edge;
    const int* e_dst = edge + E;

    // workspace layout (all 16B-aligned for the given sizes):
    // xws bf16[N*128] | xB bf16[B*128] | Wgt bf16[128*128] | W1t bf16[256*128]
    // | W2t bf16[256*256] | dinv f32[N] | deg i32[N] | off i32[N+4]
    // | slot i32[E] | srcs i32[E] | bsum i32[512]
    __bf16* xws = (__bf16*)d_ws;
    __bf16* xB  = xws + (size_t)N * 128;
    __bf16* Wgt = xB + (size_t)B * 128;
    __bf16* W1t = Wgt + 128 * 128;
    __bf16* W2t = W1t + 256 * 128;
    float* dinv = (float*)(W2t + 256 * 256);
    int*   deg  = (int*)(dinv + N);
    int*   off  = deg + N;
    int*   slot = off + (N + 4);
    int*   srcs = slot + E;
    int*   bsum = srcs + E;

    int NB = (N + 1023) / 1024;   // scan blocks (489 <= 512)

    hipMemsetAsync(deg, 0, (size_t)N * sizeof(int), stream);

    k_tconv<<<(128 * 128 + 255) / 256, 256, 0, stream>>>(W_gcn, Wgt, 7, 128 * 128, 128);
    k_tconv<<<(256 * 128 + 255) / 256, 256, 0, stream>>>(W1, W1t, 7, 256 * 128, 256);
    k_tconv<<<(256 * 256 + 255) / 256, 256, 0, stream>>>(W2, W2t, 8, 256 * 256, 256);
    k_edges<<<(E + 255) / 256, 256, 0, stream>>>(e_dst, E, deg, slot);
    k_scan1<<<NB, 256, 0, stream>>>(deg, off, bsum, N);
    k_scan2<<<1, 512, 0, stream>>>(bsum, NB);
    k_scan3<<<NB, 256, 0, stream>>>(off, bsum, N, E);
    k_dinv<<<(N + 255) / 256, 256, 0, stream>>>(deg, dinv, N);
    k_scatter<<<(E + 255) / 256, 256, 0, stream>>>(e_dst, e_src, slot, off, srcs, E);
    k_gemm<<<1024, 256, 0, stream>>>(state, Wgt, dinv, xws, N);
    k_readout<<<(B + 7) / 8, 256, 0, stream>>>(off, srcs, dinv, xws, state, b_gcn,
                                               action, xB, B);
    k_mlp<<<B / 16, 256, 0, stream>>>(xB, W1t, b1, W2t, b2, W3, b3, out, B);
}

// Round 5
// 617.758 us; speedup vs baseline: 1.1373x; 1.0263x over previous
//
#include <hip/hip_runtime.h>

// Sizes: N=500000, C=128, H=256, A=10, E=600000, B=50000.
// R6: k_gemm reg-resident W^T + double-buffered A + swapped MFMA operands.
// R7: LDS-transpose gemm epilogue; CSR graph; readout restructure.
// R8: launch_bounds(256,1) on gemm — NEUTRAL -> spill theory refuted.
// R9 (this round): graph build simplification. Degree ~ Poisson(1.2) =>
//   P(deg>8) ~ 5e-6 (~2 nodes). Replace CSR (edges+scan123+scatter, 5
//   dispatches) with fixed-K=8 inline adjacency built directly in k_edges
//   + tiny overflow list. Readout: prefetch deg+adj for all 5 nodes upfront,
//   gathers fully independent (static unrolled j with predication).
//   tconv x3 merged into 1. 13 dispatches -> 7. gemm unchanged (isolation).

typedef __bf16 bf16x8 __attribute__((ext_vector_type(8)));
typedef __bf16 bf16x4 __attribute__((ext_vector_type(4)));
typedef float f32x4 __attribute__((ext_vector_type(4)));

// ---- per-edge: degree + direct K=8 adjacency write (+ rare overflow) --------
__global__ __launch_bounds__(256) void k_edges(const int* __restrict__ dst,
                                               const int* __restrict__ src, int E,
                                               int* __restrict__ deg,
                                               int* __restrict__ adj,
                                               int* __restrict__ ovfc,
                                               int* __restrict__ ovf) {
    int e = blockIdx.x * 256 + threadIdx.x;
    if (e < E) {
        int d = dst[e];
        int s = src[e];
        int slot = atomicAdd(&deg[d], 1);
        if (slot < 8) {
            adj[(size_t)d * 8 + slot] = s;
        } else {
            int o = atomicAdd(ovfc, 1);
            ovf[2 * o] = d;
            ovf[2 * o + 1] = s;
        }
    }
}

// ---- dinv = rsqrt(deg + 1)  (+1 = self loop) --------------------------------
__global__ __launch_bounds__(256) void k_dinv(const int* __restrict__ deg,
                                              float* __restrict__ dinv, int N) {
    int i = blockIdx.x * 256 + threadIdx.x;
    if (i < N) dinv[i] = rsqrtf((float)deg[i] + 1.0f);
}

// ---- transpose-convert all three weight matrices in one launch --------------
// ranges: [0,16384) Wgcn 128x128 | [16384,49152) W1 128x256 | rest W2 256x256
__global__ __launch_bounds__(256) void k_tconv_all(const float* __restrict__ Wg,
                                                   const float* __restrict__ W1,
                                                   const float* __restrict__ W2,
                                                   __bf16* __restrict__ Wgt,
                                                   __bf16* __restrict__ W1t,
                                                   __bf16* __restrict__ W2t) {
    int i = blockIdx.x * 256 + threadIdx.x;
    if (i < 16384) {
        int n = i >> 7, k = i & 127;
        Wgt[i] = (__bf16)Wg[k * 128 + n];
    } else if (i < 49152) {
        int j = i - 16384;
        int n = j >> 7, k = j & 127;
        W1t[j] = (__bf16)W1[k * 256 + n];
    } else if (i < 114688) {
        int j = i - 49152;
        int n = j >> 8, k = j & 255;
        W2t[j] = (__bf16)W2[k * 256 + n];
    }
}

// ---- xws = bf16( dinv[row] * (state @ W_gcn) )  via MFMA 16x16x32 bf16 ------
__global__ __launch_bounds__(256, 1) void k_gemm(const float* __restrict__ X,
                                                 const __bf16* __restrict__ Wt,
                                                 const float* __restrict__ dinv,
                                                 __bf16* __restrict__ Y, int N) {
    __shared__ __bf16 st[4][16][136];   // per-wave transpose staging, +8 pad
    int wave = threadIdx.x >> 6;
    int lane = threadIdx.x & 63;
    int m = lane & 15;
    int quad = lane >> 4;
    const long NT = (long)N >> 4;                  // 16-row tiles
    const long g0 = (long)blockIdx.x * 4 + wave;   // global wave id
    const long gs = (long)gridDim.x * 4;
    if (g0 >= NT) return;

    // W^T fragments resident for the whole kernel (128 VGPRs).
    bf16x8 bfrag[8][4];
    #pragma unroll
    for (int t = 0; t < 8; t++)
        #pragma unroll
        for (int kt = 0; kt < 4; kt++)
            bfrag[t][kt] =
                *(const bf16x8*)(Wt + (t * 16 + m) * 128 + kt * 32 + quad * 8);

    auto loadA = [&](float4* BUF, long tile) {
        const float* ap = X + (tile * 16 + m) * 128 + quad * 8;
        #pragma unroll
        for (int kt = 0; kt < 4; kt++) {
            BUF[2 * kt]     = *(const float4*)(ap + kt * 32);
            BUF[2 * kt + 1] = *(const float4*)(ap + kt * 32 + 4);
        }
    };

    auto compute = [&](const float4* BUF, long tile) {
        long row = tile * 16 + m;
        float dv = dinv[row];
        f32x4 acc[8] = {};
        #pragma unroll
        for (int kt = 0; kt < 4; kt++) {
            float4 lo = BUF[2 * kt], hi = BUF[2 * kt + 1];
            bf16x8 a = {(__bf16)lo.x, (__bf16)lo.y, (__bf16)lo.z, (__bf16)lo.w,
                        (__bf16)hi.x, (__bf16)hi.y, (__bf16)hi.z, (__bf16)hi.w};
            #pragma unroll
            for (int t = 0; t < 8; t++)
                acc[t] = __builtin_amdgcn_mfma_f32_16x16x32_bf16(bfrag[t][kt], a,
                                                                 acc[t], 0, 0, 0);
        }
        // stage lane-owned row m into LDS, then read back row-major and store
        // 4 rows x 256B = 1KB fully-coalesced per instruction.
        #pragma unroll
        for (int t = 0; t < 8; t++) {
            bf16x4 o;
            #pragma unroll
            for (int r = 0; r < 4; r++) o[r] = (__bf16)(acc[t][r] * dv);
            *(bf16x4*)&st[wave][m][t * 16 + quad * 4] = o;
        }
        asm volatile("s_waitcnt lgkmcnt(0)" ::: "memory");
        __builtin_amdgcn_sched_barrier(0);
        #pragma unroll
        for (int it = 0; it < 4; it++) {
            bf16x8 v = *(const bf16x8*)&st[wave][it * 4 + quad][m * 8];
            *(bf16x8*)(Y + (tile * 16 + it * 4 + quad) * 128 + m * 8) = v;
        }
    };

    float4 A0[8], A1[8];
    loadA(A0, g0);
    long t = g0;
    while (true) {
        long t1 = t + gs;
        loadA(A1, t1 < NT ? t1 : t);      // clamped dummy prefetch at tail
        compute(A0, t);
        if (t1 >= NT) break;
        long t2 = t1 + gs;
        loadA(A0, t2 < NT ? t2 : t1);
        compute(A1, t1);
        if (t2 >= NT) break;
        t = t2;
    }
}

// ---- fused aggregate + relu + residual + action-weighted readout ------------
// 256 thr = 16 slots x 16 lanes. Block handles 8 b's; slot pair (2s,2s+1)
// covers b_local = s: slot handles nodes b*10 + (slot&1)*5 + k, k<5.
__global__ __launch_bounds__(256) void k_readout(const int* __restrict__ deg,
                                                 const int* __restrict__ adj,
                                                 const int* __restrict__ ovfc,
                                                 const int* __restrict__ ovf,
                                                 const float* __restrict__ dinv,
                                                 const __bf16* __restrict__ xws,
                                                 const float* __restrict__ state,
                                                 const float* __restrict__ bgcn,
                                                 const float* __restrict__ action,
                                                 __bf16* __restrict__ xB, int B) {
    __shared__ float red[16][132];
    int tid = threadIdx.x;
    int slot = tid >> 4;
    int lane16 = tid & 15;
    int c0 = lane16 * 8;
    int b = blockIdx.x * 8 + (slot >> 1);

    float4 bg0 = *(const float4*)(bgcn + c0);
    float4 bg1 = *(const float4*)(bgcn + c0 + 4);
    float bg[8] = {bg0.x, bg0.y, bg0.z, bg0.w, bg1.x, bg1.y, bg1.z, bg1.w};
    float acc[8] = {};

    if (b < B) {
        int nbase = b * 10 + (slot & 1) * 5;
        // prefetch degree + adjacency for all 5 nodes (independent loads)
        int dgs[5];
        int4 aj0[5], aj1[5];
        #pragma unroll
        for (int k = 0; k < 5; k++) {
            int n = nbase + k;
            dgs[k] = deg[n];
            aj0[k] = *(const int4*)(adj + (size_t)n * 8);
            aj1[k] = *(const int4*)(adj + (size_t)n * 8 + 4);
        }
        #pragma unroll
        for (int k = 0; k < 5; k++) {
            int n = nbase + k;
            int dg = dgs[k];
            bf16x8 x = *(const bf16x8*)(xws + (size_t)n * 128 + c0);
            float s[8];
            #pragma unroll
            for (int i = 0; i < 8; i++) s[i] = (float)x[i];
            int nb[8] = {aj0[k].x, aj0[k].y, aj0[k].z, aj0[k].w,
                         aj1[k].x, aj1[k].y, aj1[k].z, aj1[k].w};
            #pragma unroll
            for (int j = 0; j < 8; j++) {
                if (j < dg) {
                    bf16x8 g = *(const bf16x8*)(xws + (size_t)nb[j] * 128 + c0);
                    #pragma unroll
                    for (int i = 0; i < 8; i++) s[i] += (float)g[i];
                }
            }
            if (dg > 8) {             // ~2-3 nodes in 500K: scan overflow list
                int c = *ovfc;
                for (int o = 0; o < c; o++) {
                    if (ovf[2 * o] == n) {
                        bf16x8 g =
                            *(const bf16x8*)(xws + (size_t)ovf[2 * o + 1] * 128 + c0);
                        #pragma unroll
                        for (int i = 0; i < 8; i++) s[i] += (float)g[i];
                    }
                }
            }
            float di = dinv[n];
            float aw = action[n] * 10.f;
            float4 st0 = *(const float4*)(state + (size_t)n * 128 + c0);
            float4 st1 = *(const float4*)(state + (size_t)n * 128 + c0 + 4);
            float stv[8] = {st0.x, st0.y, st0.z, st0.w,
                            st1.x, st1.y, st1.z, st1.w};
            #pragma unroll
            for (int i = 0; i < 8; i++)
                acc[i] += aw * (fmaxf(di * s[i] + bg[i], 0.f) + stv[i]);
        }
    }
    f32x4 va = {acc[0], acc[1], acc[2], acc[3]};
    f32x4 vb = {acc[4], acc[5], acc[6], acc[7]};
    *(f32x4*)&red[slot][c0] = va;
    *(f32x4*)&red[slot][c0 + 4] = vb;
    __syncthreads();
    // 8 b x 128 ch outputs; thread t: b_local = t>>5, 4 consecutive channels
    int bl = tid >> 5;
    int ch0 = (tid & 31) * 4;
    int b2 = blockIdx.x * 8 + bl;
    if (b2 < B) {
        bf16x4 o;
        #pragma unroll
        for (int c = 0; c < 4; c++)
            o[c] = (__bf16)(red[2 * bl][ch0 + c] + red[2 * bl + 1][ch0 + c]);
        *(bf16x4*)(xB + (size_t)b2 * 128 + ch0) = o;
    }
}

// ---- MLP head via MFMA: relu(x@W1+b1) -> relu(@W2+b2) -> @W3+b3 -------------
__global__ __launch_bounds__(256) void k_mlp(const __bf16* __restrict__ xB,
                                             const __bf16* __restrict__ W1t,
                                             const float* __restrict__ b1,
                                             const __bf16* __restrict__ W2t,
                                             const float* __restrict__ b2,
                                             const float* __restrict__ W3,
                                             const float* __restrict__ b3,
                                             float* __restrict__ out, int B) {
    __shared__ __bf16 hs[16][264];
    __shared__ float osum[4][16];
    int wave = threadIdx.x >> 6;
    int lane = threadIdx.x & 63;
    int m = lane & 15;
    int quad = lane >> 4;
    long r0 = (long)blockIdx.x * 16;

    f32x4 acc[4] = {};
    #pragma unroll
    for (int kt = 0; kt < 4; kt++) {
        int k0 = kt * 32 + quad * 8;
        bf16x8 a = *(const bf16x8*)(xB + (r0 + m) * 128 + k0);
        #pragma unroll
        for (int t = 0; t < 4; t++) {
            int n = wave * 64 + t * 16 + m;
            bf16x8 b = *(const bf16x8*)(W1t + (long)n * 128 + k0);
            acc[t] = __builtin_amdgcn_mfma_f32_16x16x32_bf16(a, b, acc[t], 0, 0, 0);
        }
    }
    #pragma unroll
    for (int t = 0; t < 4; t++) {
        int n = wave * 64 + t * 16 + m;
        float bb = b1[n];
        #pragma unroll
        for (int r = 0; r < 4; r++)
            hs[quad * 4 + r][n] = (__bf16)fmaxf(acc[t][r] + bb, 0.f);
    }
    __syncthreads();

    f32x4 acc2[4] = {};
    #pragma unroll
    for (int kt = 0; kt < 8; kt++) {
        int k0 = kt * 32 + quad * 8;
        bf16x8 a = *(const bf16x8*)(&hs[m][k0]);
        #pragma unroll
        for (int t = 0; t < 4; t++) {
            int n = wave * 64 + t * 16 + m;
            bf16x8 b = *(const bf16x8*)(W2t + (long)n * 256 + k0);
            acc2[t] = __builtin_amdgcn_mfma_f32_16x16x32_bf16(a, b, acc2[t], 0, 0, 0);
        }
    }

    float part[4] = {0.f, 0.f, 0.f, 0.f};
    #pragma unroll
    for (int t = 0; t < 4; t++) {
        int n = wave * 64 + t * 16 + m;
        float bb = b2[n], w3 = W3[n];
        #pragma unroll
        for (int r = 0; r < 4; r++)
            part[r] += fmaxf(acc2[t][r] + bb, 0.f) * w3;
    }
    #pragma unroll
    for (int off = 8; off; off >>= 1)
        #pragma unroll
        for (int r = 0; r < 4; r++)
            part[r] += __shfl_down(part[r], off, 16);
    if (m == 0) {
        #pragma unroll
        for (int r = 0; r < 4; r++) osum[wave][quad * 4 + r] = part[r];
    }
    __syncthreads();
    if (threadIdx.x < 16)
        out[r0 + threadIdx.x] = osum[0][threadIdx.x] + osum[1][threadIdx.x] +
                                osum[2][threadIdx.x] + osum[3][threadIdx.x] + b3[0];
}

extern "C" void kernel_launch(void* const* d_in, const int* in_sizes, int n_in,
                              void* d_out, int out_size, void* d_ws, size_t ws_size,
                              hipStream_t stream) {
    const float* state  = (const float*)d_in[0];
    const int*   edge   = (const int*)d_in[1];   // [2, E]: src row then dst row
    const float* action = (const float*)d_in[2];
    const float* W_gcn  = (const float*)d_in[3];
    const float* b_gcn  = (const float*)d_in[4];
    const float* W1     = (const float*)d_in[5];
    const float* b1     = (const float*)d_in[6];
    const float* W2     = (const float*)d_in[7];
    const float* b2     = (const float*)d_in[8];
    const float* W3     = (const float*)d_in[9];
    const float* b3     = (const float*)d_in[10];
    float* out = (float*)d_out;

    int N = in_sizes[0] / 128;
    int E = in_sizes[1] / 2;
    int B = out_size;
    const int* e_src = edge;
    const int* e_dst = edge + E;

    // workspace layout (16B-aligned for the given sizes):
    // xws bf16[N*128] | xB bf16[B*128] | Wgt bf16[128*128] | W1t bf16[256*128]
    // | W2t bf16[256*256] | dinv f32[N] | deg i32[N] | ovfc i32[4]
    // | adj i32[N*8] | ovf i32[2*E]
    __bf16* xws = (__bf16*)d_ws;
    __bf16* xB  = xws + (size_t)N * 128;
    __bf16* Wgt = xB + (size_t)B * 128;
    __bf16* W1t = Wgt + 128 * 128;
    __bf16* W2t = W1t + 256 * 128;
    float* dinv = (float*)(W2t + 256 * 256);
    int*   deg  = (int*)(dinv + N);
    int*   ovfc = deg + N;
    int*   adj  = ovfc + 4;
    int*   ovf  = adj + (size_t)N * 8;

    // zero deg + ovfc in one memset
    hipMemsetAsync(deg, 0, ((size_t)N + 4) * sizeof(int), stream);

    k_tconv_all<<<448, 256, 0, stream>>>(W_gcn, W1, W2, Wgt, W1t, W2t);
    k_edges<<<(E + 255) / 256, 256, 0, stream>>>(e_dst, e_src, E, deg, adj, ovfc, ovf);
    k_dinv<<<(N + 255) / 256, 256, 0, stream>>>(deg, dinv, N);
    k_gemm<<<1024, 256, 0, stream>>>(state, Wgt, dinv, xws, N);
    k_readout<<<(B + 7) / 8, 256, 0, stream>>>(deg, adj, ovfc, ovf, dinv, xws,
                                               state, b_gcn, action, xB, B);
    k_mlp<<<B / 16, 256, 0, stream>>>(xB, W1t, b1, W2t, b2, W3, b3, out, B);
}